// Round 4
// baseline (3384.568 us; speedup 1.0000x reference)
//
#include <hip/hip_runtime.h>
#include <utility>

#define LMAX 8
#define NENT 249
#define NFULL 215
#define NPAIR 45
#define EPB 128            // batch elements per block (2 per lane, f32x2-packed)
#define TPB 512            // 8 waves
#define ESTR 130           // padded elem stride (floats)
#define NCO 45             // sum_{l<=8}(l+1)
#define PLANE (NCO*ESTR)
// staged-mode constants (round-0 verified layout)
#define P1END 30
#define FSPLIT 100
#define PSLOT 115
#define NSLOT 149

typedef __attribute__((ext_vector_type(2))) float f32x2;

struct P2 { int l1, l2; };

__host__ __device__ constexpr int tri_(int l){ return l*(l+1)/2; }
// F_l^{m} for m<0 equals (sr*Re, sq*Im) of the stored value at |m| (m>=1 only;
// m=0 is a full complex value — NO reality constraint).
__host__ __device__ constexpr int sr_(int m){ return m>=0 ? 1 : (((-m)&1)? -1 : 1); }
__host__ __device__ constexpr int sq_(int m){ return m>=0 ? 1 : (((-m)&1)? 1 : -1); }

__host__ __device__ constexpr P2 pair_of(int w){
  int n=0;
  for(int a=0;a<=LMAX;a++) for(int b=a;b<=LMAX;b++){ if(n==w) return P2{a,b}; n++; }
  return P2{0,0};
}

// index of (l1,l2,lo) in FULL_MAP generation order
__host__ __device__ constexpr int full_rank(int l1,int l2,int lo){
  int r=0;
  for(int a=0;a<=LMAX;a++) for(int b=a;b<=LMAX;b++){
    int hi=a+b>LMAX?LMAX:a+b;
    for(int c=b-a;c<=hi;c++){ if(a==l1&&b==l2&&c==lo) return r; r++; }
  }
  return -1;
}

// index of (l1,l2,lo) in POWER_MAP generation order; -1 if not a POWER entry
__host__ __device__ constexpr int power_idx(int l1,int l2,int lo){
  int n=0;
  for(int b=2;b<=LMAX;b++){
    if(l1==1&&l2==b&&lo==b-1) return n; n++;
    if(b>=4){ if(l1==1&&l2==b&&lo==b) return n; n++; }
  }
  for(int b=3;b<=LMAX;b++){
    if(l1==2&&l2==b&&lo==b-2) return n; n++;
    if(l1==2&&l2==b&&lo==b-1) return n; n++;
  }
  if(l1==3&&l2==3&&lo==2) return n; n++;
  for(int b=4;b<=LMAX;b++){
    if(l1==3&&l2==b&&lo==b-3) return n; n++;
    if((b&1)&&b>=5){
      if(l1==3&&l2==b&&lo==b-2) return n; n++;
      if(l1==3&&l2==b&&lo==b-1) return n; n++;
    }
  }
  return -1;
}

// ---- cost model (host schedule) --------------------------------------------
__host__ __device__ constexpr double pair_w(int p){
  P2 pe = pair_of(p);
  int L1=pe.l1, L2=pe.l2;
  int LOmx=(L1+L2<LMAX)?(L1+L2):LMAX, LOmn=L2-L1;
  double ww = 2.0*(L1+L2+2);
  for (int M=-LOmx;M<=LOmx;M++){
    int lo_ = (M-L2>-L1)?(M-L2):-L1, hi_ = (M+L2<L1)?(M+L2):L1;
    int dn = hi_-lo_+1;
    ww += 4.0*dn;
    int aM = M<0?-M:M;
    for (int lo=(LOmn>aM?LOmn:aM); lo<=LOmx; lo++)
      ww += 2.0*dn + 2.0 + (power_idx(L1,L2,lo)>=0 ? 2.0 : 0.0);
  }
  return ww;
}

// ---- compile-time Clebsch-Gordan -------------------------------------------
__host__ __device__ constexpr double csqrt_(double x){
  if (x<=0.0) return 0.0;
  double v=x, s=1.0;
  while (v>4.0){ v*=0.25; s*=2.0; }
  while (v<0.25){ v*=4.0; s*=0.5; }
  double g=v;
  for(int i=0;i<48;i++) g=0.5*(g+v/g);
  return g*s;
}
__host__ __device__ constexpr double cgC(int j1,int m1,int j2,int m2,int j3,int m3){
  if (m1+m2 != m3) return 0.0;
  int dj=j1-j2; if(dj<0)dj=-dj;
  if (j3<dj || j3>j1+j2) return 0.0;
  if (m2<-j2 || m2>j2 || m1<-j1 || m1>j1 || m3<-j3 || m3>j3) return 0.0;
  double f[26]={}; f[0]=1.0;
  for(int t=1;t<26;t++) f[t]=f[t-1]*(double)t;
  double pre = csqrt_((2.0*j3+1.0)*f[j1+j2-j3]*f[j1-j2+j3]*f[-j1+j2+j3]/f[j1+j2+j3+1]);
  pre *= csqrt_(f[j1+m1]*f[j1-m1]*f[j2+m2]*f[j2-m2]*f[j3+m3]*f[j3-m3]);
  int kmin=0; if(j2-j3-m1>kmin)kmin=j2-j3-m1; if(j1-j3+m2>kmin)kmin=j1-j3+m2;
  int kmax=j1+j2-j3; if(j1-m1<kmax)kmax=j1-m1; if(j2+m2<kmax)kmax=j2+m2;
  double s=0.0;
  for(int k=kmin;k<=kmax;k++){
    double term = 1.0/(f[k]*f[j1+j2-j3-k]*f[j1-m1-k]*f[j2+m2-k]*f[j3-j2+m1+k]*f[j3-j1-m2+k]);
    s += (k&1)? -term : term;
  }
  return pre*s;
}

template<int L1,int L2>
struct CGTab {
  static constexpr int LOmx = (L1+L2<LMAX)?(L1+L2):LMAX;
  static constexpr int LOmn = L2-L1;
  static constexpr int NLO  = LOmx-LOmn+1;
  float c[NLO][2*LOmx+1][2*L1+1];   // [lo-LOmn][M+LOmx][m1+L1]
};
template<int L1,int L2>
__host__ __device__ constexpr CGTab<L1,L2> make_cgtab(){
  CGTab<L1,L2> T{};
  for(int lo=T.LOmn; lo<=T.LOmx; lo++)
    for(int M=-T.LOmx; M<=T.LOmx; M++)
      for(int m1=-L1;m1<=L1;m1++){
        double v=0.0;
        if (M>=-lo && M<=lo){
          int m2=M-m1;
          if(m2>=-L2&&m2<=L2) v = cgC(L1,m1,L2,m2,lo,M);
        }
        T.c[lo-T.LOmn][M+T.LOmx][m1+L1] = (float)v;
      }
  return T;
}

// volatile LDS load: defeats load-CSE so the compiler cannot re-materialize
// the F register caches (which is exactly what spilled in round 0).
// LDS re-read ~5 cyc << scratch spill ~900 cyc.
__device__ __attribute__((always_inline)) inline f32x2 vld(const float* p){
  return *(const volatile f32x2*)p;
}

// ---- per-pair compute (FULL M range; bounded-register form) ----------------
// F1/F2/F3 are read from LDS at point of use (volatile). Live set:
// Prd/Pid (<= 2*(2*L1+1) f32x2) + bAcc/pAcc + temps  ->  ~106 VGPR worst (8,8).
// direct==1: emit to wsTd[(size_t)entry*B] (coalesced 512B wave stores).
// direct==0: emit to LDS stage (round-0 verified staged layout).
template<int PI>
__device__ __attribute__((always_inline)) inline void do_pair(
    const float* __restrict__ lds, float* __restrict__ stage,
    float* __restrict__ wsTd, size_t B, int direct, int lane2)
{
  constexpr P2 pe = pair_of(PI);
  constexpr int L1 = pe.l1, L2 = pe.l2;
  constexpr int LOmin = L2-L1;
  constexpr int LOmax = (L1+L2<LMAX)?(L1+L2):LMAX;
  constexpr int NLO = LOmax-LOmin+1;
  constexpr int B1 = tri_(L1), B2 = tri_(L2);
  constexpr auto tab = make_cgtab<L1,L2>();

  f32x2 bAcc[NLO], pAcc[NLO];
#pragma unroll
  for (int t=0;t<NLO;t++){ bAcc[t]=f32x2{0.f,0.f}; pAcc[t]=f32x2{0.f,0.f}; }

#pragma unroll
  for (int M=-LOmax; M<=LOmax; M++){
    const int m1lo = (M-L2 > -L1) ? (M-L2) : -L1;
    const int m1hi = (M+L2 <  L1) ? (M+L2) :  L1;
    f32x2 Prd[2*L1+1], Pid[2*L1+1];
#pragma unroll
    for (int m1=-L1; m1<=L1; m1++){
      if (m1<m1lo || m1>m1hi) continue;     // folds after unroll
      const int i  = m1-m1lo;
      const int m2 = M-m1;
      const int a1 = m1<0?-m1:m1, a2 = m2<0?-m2:m2;
      const int s1 = sr_(m1)*sr_(m2);
      const int s2 = -(sq_(m1)*sq_(m2));
      const int s3 = sr_(m1)*sq_(m2);
      const int s4 = sq_(m1)*sr_(m2);
      f32x2 x1 = vld(&lds[(B1+a1)*ESTR + lane2]);
      f32x2 y1 = vld(&lds[PLANE + (B1+a1)*ESTR + lane2]);
      f32x2 x2 = vld(&lds[(B2+a2)*ESTR + lane2]);
      f32x2 y2 = vld(&lds[PLANE + (B2+a2)*ESTR + lane2]);
      f32x2 t1 = (s1>0? x1 : -x1) * x2;
      Prd[i] = __builtin_elementwise_fma((s2>0? y1 : -y1), y2, t1);
      f32x2 t2 = (s3>0? x1 : -x1) * y2;
      Pid[i] = __builtin_elementwise_fma((s4>0? y1 : -y1), x2, t2);
    }
#pragma unroll
    for (int lo=LOmin; lo<=LOmax; lo++){
      if (lo < (M<0?-M:M)) continue;        // G_M only exists for |M|<=lo
      f32x2 Gr = {0.f,0.f}, Gi = {0.f,0.f};
#pragma unroll
      for (int m1=-L1; m1<=L1; m1++){
        if (m1<m1lo || m1>m1hi) continue;
        const int i = m1-m1lo;
        const float C = tab.c[lo-LOmin][M+LOmax][m1+L1];
        if (C != 0.f){
          f32x2 Cv = {C,C};
          Gr = __builtin_elementwise_fma(Cv, Prd[i], Gr);
          Gi = __builtin_elementwise_fma(Cv, Pid[i], Gi);
        }
      }
      // beta += Re(G_M * conj(F3_M)); F3_M = (sr*x3, sq*y3) with x3,y3 at |M|
      const int aM = M<0?-M:M;
      const int B3 = tri_(lo);
      f32x2 x3 = vld(&lds[(B3+aM)*ESTR + lane2]);
      f32x2 y3 = vld(&lds[PLANE + (B3+aM)*ESTR + lane2]);
      const int AL = sr_(M), BE = sq_(M);   // fold after unroll
      bAcc[lo-LOmin] = __builtin_elementwise_fma(Gr, (AL>0? x3 : -x3), bAcc[lo-LOmin]);
      bAcc[lo-LOmin] = __builtin_elementwise_fma(Gi, (BE>0? y3 : -y3), bAcc[lo-LOmin]);
      if (power_idx(L1,L2,lo) >= 0){        // compile-time condition
        pAcc[lo-LOmin] = __builtin_elementwise_fma(Gr, Gr, pAcc[lo-LOmin]);
        pAcc[lo-LOmin] = __builtin_elementwise_fma(Gi, Gi, pAcc[lo-LOmin]);
      }
    }
  }

  // emit (wave-uniform runtime branch; pair-disjoint destinations, no races)
#pragma unroll
  for (int lo=LOmin; lo<=LOmax; lo++){
    const int fr   = full_rank(L1,L2,lo);
    const int pidx = power_idx(L1,L2,lo);
    if (direct){
      *(f32x2*)&wsTd[(size_t)fr*B] = bAcc[lo-LOmin];
      if (pidx>=0)
        *(f32x2*)&wsTd[(size_t)(NFULL+pidx)*B] = pAcc[lo-LOmin];
    } else {
      const int slot = fr<FSPLIT ? fr : fr-FSPLIT;   // phase-1 pairs all have fr<100
      *(f32x2*)&stage[slot*ESTR + lane2] = bAcc[lo-LOmin];
      if (pidx>=0)
        *(f32x2*)&stage[(PSLOT+pidx)*ESTR + lane2] = pAcc[lo-LOmin];
    }
  }
}

// ---- masked dispatch (per-wave LPT bitmask schedule) -----------------------
template<int PI>
__device__ __attribute__((always_inline)) inline void pair_mstep(
    const float* __restrict__ lds, float* __restrict__ stage,
    float* __restrict__ wsTd, size_t B, int direct, int lane2,
    unsigned long long mk)
{
  if ((mk>>PI)&1ull) do_pair<PI>(lds, stage, wsTd, B, direct, lane2);  // wave-uniform
}
template<int OFF, int... Ps>
__device__ __attribute__((always_inline)) inline void pair_masked(
    std::integer_sequence<int,Ps...>,
    const float* __restrict__ lds, float* __restrict__ stage,
    float* __restrict__ wsTd, size_t B, int direct, int lane2,
    unsigned long long mk)
{
  (pair_mstep<OFF+Ps>(lds, stage, wsTd, B, direct, lane2, mk), ...);
}

struct Msk2 { unsigned long long a[8]; unsigned long long b[8]; };

constexpr int D_LDS_BYTES = 2*PLANE*4;                    // 46,800 B (direct)
constexpr int S_LDS_FLOATS = 2*PLANE + NSLOT*ESTR;
constexpr int S_LDS_BYTES  = S_LDS_FLOATS*4;              // 124,280 B (staged)
static_assert(S_LDS_BYTES <= 160*1024, "LDS over 160KB");

// ================= compute kernel (direct or staged, runtime flag) ==========
__global__ __launch_bounds__(TPB, 2) void compute_kernel(
    const float* __restrict__ re, const float* __restrict__ im,
    float* __restrict__ wsT, float* __restrict__ out,
    int Bc, Msk2 msk, int direct)
{
  extern __shared__ float lds[];
  float* stage = lds + 2*PLANE;            // only valid/used when !direct
  const int gbase = blockIdx.x*EPB;

  // stage the m<=l triangle of 128 elements into [coeff][elem] planes
  for (int t=threadIdx.x; t<EPB*81; t+=TPB){
    float vr = re[(size_t)gbase*81 + t];
    float vi = im[(size_t)gbase*81 + t];
    int elem = t/81, x = t - elem*81;
    int l = x/9, m = x - l*9;
    if (m<=l){
      int off = tri_(l)+m;
      lds[off*ESTR+elem] = vr;
      lds[PLANE + off*ESTR+elem] = vi;
    }
  }
  __syncthreads();

  const int lane  = threadIdx.x & 63;
  const int wv    = __builtin_amdgcn_readfirstlane(threadIdx.x >> 6);
  const int lane2 = lane*2;
  const unsigned long long mkA = msk.a[wv];
  const unsigned long long mkB = msk.b[wv];
  float* wsTd = wsT ? (wsT + gbase + lane2) : stage;
  const long long obase = (long long)gbase*NENT;

  // group A: pairs [0,30) (l1<=3; staged: FULL ranks [0,100) + POWER slots)
  pair_masked<0>(std::make_integer_sequence<int,P1END>{},
                 lds, stage, wsTd, (size_t)Bc, direct, lane2, mkA);
  if (!direct){
    __syncthreads();
    // flush A: out entries [0,100) per element (coalesced 400B runs)
    for (int p=threadIdx.x; p<EPB*FSPLIT; p+=TPB){
      int elem = p/FSPLIT, o = p - elem*FSPLIT;
      out[obase + (long long)elem*NENT + o] = stage[o*ESTR + elem];
    }
    __syncthreads();
  }

  // group B: pairs [30,45) (l1>=4; staged: FULL ranks [100,215) -> slots [0,115))
  pair_masked<P1END>(std::make_integer_sequence<int,NPAIR-P1END>{},
                     lds, stage, wsTd, (size_t)Bc, direct, lane2, mkB);
  if (!direct){
    __syncthreads();
    // flush B: out entries [100,249) <- slots [0,149) (coalesced 596B runs)
    for (int p=threadIdx.x; p<EPB*NSLOT; p+=TPB){
      int elem = p/NSLOT, o = p - elem*NSLOT;
      out[obase + (long long)elem*NENT + FSPLIT + o] = stage[o*ESTR + elem];
    }
  }
}

// ================= transpose kernel (wsT[o][e] -> out[e][o]) ================
__global__ __launch_bounds__(256) void transpose_kernel(
    const float* __restrict__ wsT, float* __restrict__ out, int B)
{
  __shared__ float tile[64][65];
  const int o0 = blockIdx.x * 64;
  const int e0 = blockIdx.y * 64;
  for (int k=threadIdx.x; k<64*64; k+=256){
    int r = k>>6, c = k&63;              // r: entry offset, c: elem offset
    int o = o0+r;
    tile[r][c] = (o<NENT) ? wsT[(size_t)o*B + e0 + c] : 0.f;
  }
  __syncthreads();
  for (int k=threadIdx.x; k<64*64; k+=256){
    int r = k>>6, c = k&63;              // r: elem offset, c: entry offset
    int o = o0+c;
    if (o<NENT) out[(size_t)(e0+r)*NENT + o] = tile[c][r];
  }
}

// ================= host ====================================================
extern "C" void kernel_launch(void* const* d_in, const int* in_sizes, int n_in,
                              void* d_out, int out_size, void* d_ws, size_t ws_size,
                              hipStream_t stream) {
  const float* re = (const float*)d_in[0];
  const float* im = (const float*)d_in[1];
  float* out = (float*)d_out;
  const int batch = in_sizes[0] / 81;

  hipFuncSetAttribute((const void*)compute_kernel,
                      hipFuncAttributeMaxDynamicSharedMemorySize, S_LDS_BYTES);

  // per-wave LPT schedule within each pair group (A: [0,30), B: [30,45))
  Msk2 msk{};
  {
    double w[NPAIR]; int order[NPAIR];
    for (int p=0;p<NPAIR;p++){ w[p]=pair_w(p); order[p]=p; }
    for (int i=0;i<NPAIR;i++){            // selection sort desc by weight
      int mx=i;
      for (int j=i+1;j<NPAIR;j++) if (w[order[j]]>w[order[mx]]) mx=j;
      int t=order[i]; order[i]=order[mx]; order[mx]=t;
    }
    double loadA[8]={}, loadB[8]={};
    for (int i=0;i<NPAIR;i++){
      int p = order[i];
      if (p < P1END){
        int b=0; for (int j=1;j<8;j++) if (loadA[j]<loadA[b]) b=j;
        msk.a[b] |= 1ull<<p; loadA[b] += w[p];
      } else {
        int b=0; for (int j=1;j<8;j++) if (loadB[j]<loadB[b]) b=j;
        msk.b[b] |= 1ull<<p; loadB[b] += w[p];
      }
    }
  }

  const size_t entry_bytes = (size_t)NENT*sizeof(float);
  if (d_ws != nullptr && ws_size >= (size_t)EPB*entry_bytes && (batch % EPB)==0){
    // ---- direct path: compute -> wsT[entry][elem] chunk, then transpose ----
    long long maxBc = (long long)(ws_size / entry_bytes);
    int Bc = (int)((maxBc/EPB)*EPB);
    if (Bc > batch) Bc = batch;
    float* wsT = (float*)d_ws;
    for (int off=0; off<batch; off+=Bc){
      int cur = (batch-off < Bc) ? (batch-off) : Bc;   // multiple of EPB
      compute_kernel<<<cur/EPB, TPB, D_LDS_BYTES, stream>>>(
          re + (size_t)off*81, im + (size_t)off*81, wsT, nullptr, cur, msk, 1);
      dim3 tg((NENT+63)/64, cur/64);
      transpose_kernel<<<tg, 256, 0, stream>>>(wsT, out + (size_t)off*NENT, cur);
    }
  } else {
    // ---- staged path (no workspace): round-0 verified flow -----------------
    compute_kernel<<<batch/EPB, TPB, S_LDS_BYTES, stream>>>(
        re, im, nullptr, out, batch, msk, 0);
  }
}

// Round 5
// 538.036 us; speedup vs baseline: 6.2906x; 6.2906x over previous
//
#include <hip/hip_runtime.h>
#include <utility>

#define LMAX 8
#define NENT 249
#define NPAIR 45
#define EPB 128            // batch elements per block (2 per lane, f32x2-packed)
#define TPB 512            // 8 waves; LDS (124KB) -> 1 block/CU regardless
#define ESTR 130           // padded elem stride (floats)
#define NCO 45             // sum_{l<=8}(l+1)
#define PLANE (NCO*ESTR)
#define P1END 30           // pairs [0,30) have l1<=3 -> FULL ranks [0,100)
#define FSPLIT 100         // FULL-rank phase split
#define PSLOT 115          // POWER slots base (phase-2 FULL uses slots [0,115))
#define NSLOT 149          // total stage slots

typedef __attribute__((ext_vector_type(2))) float f32x2;

struct P2 { int l1, l2; };

__host__ __device__ constexpr int tri_(int l){ return l*(l+1)/2; }
// F_l^{m} for m<0 equals (sr*Re, sq*Im) of the stored value at |m| (m>=1 only;
// m=0 is a full complex value — NO reality constraint).
__host__ __device__ constexpr int sr_(int m){ return m>=0 ? 1 : (((-m)&1)? -1 : 1); }
__host__ __device__ constexpr int sq_(int m){ return m>=0 ? 1 : (((-m)&1)? 1 : -1); }

__host__ __device__ constexpr P2 pair_of(int w){
  int n=0;
  for(int a=0;a<=LMAX;a++) for(int b=a;b<=LMAX;b++){ if(n==w) return P2{a,b}; n++; }
  return P2{0,0};
}

// index of (l1,l2,lo) in FULL_MAP generation order
__host__ __device__ constexpr int full_rank(int l1,int l2,int lo){
  int r=0;
  for(int a=0;a<=LMAX;a++) for(int b=a;b<=LMAX;b++){
    int hi=a+b>LMAX?LMAX:a+b;
    for(int c=b-a;c<=hi;c++){ if(a==l1&&b==l2&&c==lo) return r; r++; }
  }
  return -1;
}

// index of (l1,l2,lo) in POWER_MAP generation order; -1 if not a POWER entry.
// NOTE: POWER entries exist ONLY for l1 in {1,2,3} — this is what makes the
// |m1|-chunk split of l1>=6 pairs exact (beta is linear in the m1 partial sum;
// |G|^2 would not be, but never occurs for split pairs).
__host__ __device__ constexpr int power_idx(int l1,int l2,int lo){
  int n=0;
  for(int b=2;b<=LMAX;b++){
    if(l1==1&&l2==b&&lo==b-1) return n; n++;
    if(b>=4){ if(l1==1&&l2==b&&lo==b) return n; n++; }
  }
  for(int b=3;b<=LMAX;b++){
    if(l1==2&&l2==b&&lo==b-2) return n; n++;
    if(l1==2&&l2==b&&lo==b-1) return n; n++;
  }
  if(l1==3&&l2==3&&lo==2) return n; n++;
  for(int b=4;b<=LMAX;b++){
    if(l1==3&&l2==b&&lo==b-3) return n; n++;
    if((b&1)&&b>=5){
      if(l1==3&&l2==b&&lo==b-2) return n; n++;
      if(l1==3&&l2==b&&lo==b-1) return n; n++;
    }
  }
  return -1;
}

// ---- |m1|-chunk machinery for register-heavy pairs -------------------------
// CK=0: full m1 range. CK=1: |m1| <= L1/2. CK=2: |m1| > L1/2.
__host__ __device__ constexpr bool is_sp(int p){ return pair_of(p).l1 >= 6; }
__host__ __device__ constexpr bool in_ck(int CK,int L1,int m1){
  int a = m1<0?-m1:m1;
  return CK==0 || (CK==1 ? (a<=L1/2) : (a>L1/2));
}
__host__ __device__ constexpr int ck_dn(int CK,int L1,int L2,int M){
  int lo = (M-L2>-L1)?(M-L2):-L1, hi = (M+L2<L1)?(M+L2):L1;
  int n=0; for(int m1=lo;m1<=hi;m1++) if(in_ck(CK,L1,m1)) n++;
  return n;
}

__host__ __device__ constexpr int n_units(){
  int n=P1END;
  for(int p=P1END;p<NPAIR;p++) n += is_sp(p)?2:1;
  return n;
}
constexpr int NUNITS = n_units();   // 30 + 9 + 6*2 = 51

__host__ __device__ constexpr int unit_pair(int u){
  if (u<P1END) return u;
  int n=P1END;
  for(int p=P1END;p<NPAIR;p++){ int c=is_sp(p)?2:1; if(u<n+c) return p; n+=c; }
  return NPAIR-1;
}
__host__ __device__ constexpr int unit_chunk(int u){
  if (u<P1END) return 0;
  int n=P1END;
  for(int p=P1END;p<NPAIR;p++){ int c=is_sp(p)?2:1; if(u<n+c) return is_sp(p)?(u-n+1):0; n+=c; }
  return 0;
}

// ---- cost model (host schedule) --------------------------------------------
__host__ double pair_w_ck(int p,int ck){
  P2 pe = pair_of(p);
  int L1=pe.l1, L2=pe.l2;
  int LOmx=(L1+L2<LMAX)?(L1+L2):LMAX, LOmn=L2-L1;
  double ww = 2.0*(L1+L2+2);
  for (int M=-LOmx;M<=LOmx;M++){
    int dn = ck_dn(ck,L1,L2,M);
    if (!dn) continue;
    ww += 4.0*dn;
    int aM = M<0?-M:M;
    for (int lo=(LOmn>aM?LOmn:aM); lo<=LOmx; lo++)
      ww += 2.0*dn + 2.0 + (power_idx(L1,L2,lo)>=0 ? 2.0 : 0.0);
  }
  return ww;
}

// ---- compile-time Clebsch-Gordan -------------------------------------------
__host__ __device__ constexpr double csqrt_(double x){
  if (x<=0.0) return 0.0;
  double v=x, s=1.0;
  while (v>4.0){ v*=0.25; s*=2.0; }
  while (v<0.25){ v*=4.0; s*=0.5; }
  double g=v;
  for(int i=0;i<48;i++) g=0.5*(g+v/g);
  return g*s;
}
__host__ __device__ constexpr double cgC(int j1,int m1,int j2,int m2,int j3,int m3){
  if (m1+m2 != m3) return 0.0;
  int dj=j1-j2; if(dj<0)dj=-dj;
  if (j3<dj || j3>j1+j2) return 0.0;
  if (m2<-j2 || m2>j2 || m1<-j1 || m1>j1 || m3<-j3 || m3>j3) return 0.0;
  double f[26]={}; f[0]=1.0;
  for(int t=1;t<26;t++) f[t]=f[t-1]*(double)t;
  double pre = csqrt_((2.0*j3+1.0)*f[j1+j2-j3]*f[j1-j2+j3]*f[-j1+j2+j3]/f[j1+j2+j3+1]);
  pre *= csqrt_(f[j1+m1]*f[j1-m1]*f[j2+m2]*f[j2-m2]*f[j3+m3]*f[j3-m3]);
  int kmin=0; if(j2-j3-m1>kmin)kmin=j2-j3-m1; if(j1-j3+m2>kmin)kmin=j1-j3+m2;
  int kmax=j1+j2-j3; if(j1-m1<kmax)kmax=j1-m1; if(j2+m2<kmax)kmax=j2+m2;
  double s=0.0;
  for(int k=kmin;k<=kmax;k++){
    double term = 1.0/(f[k]*f[j1+j2-j3-k]*f[j1-m1-k]*f[j2+m2-k]*f[j3-j2+m1+k]*f[j3-j1-m2+k]);
    s += (k&1)? -term : term;
  }
  return pre*s;
}

template<int L1,int L2>
struct CGTab {
  static constexpr int LOmx = (L1+L2<LMAX)?(L1+L2):LMAX;
  static constexpr int LOmn = L2-L1;
  static constexpr int NLO  = LOmx-LOmn+1;
  float c[NLO][2*LOmx+1][2*L1+1];   // [lo-LOmn][M+LOmx][m1+L1]
};
template<int L1,int L2>
__host__ __device__ constexpr CGTab<L1,L2> make_cgtab(){
  CGTab<L1,L2> T{};
  for(int lo=T.LOmn; lo<=T.LOmx; lo++)
    for(int M=-T.LOmx; M<=T.LOmx; M++)
      for(int m1=-L1;m1<=L1;m1++){
        double v=0.0;
        if (M>=-lo && M<=lo){
          int m2=M-m1;
          if(m2>=-L2&&m2<=L2) v = cgC(L1,m1,L2,m2,lo,M);
        }
        T.c[lo-T.LOmn][M+T.LOmx][m1+L1] = (float)v;
      }
  return T;
}

// ---- per-pair compute (FULL M range, no symmetry assumptions) --------------
// CK==0: plain stage write (pair owns its slots).
// CK>0 : |m1|-chunk partial; beta partials atomicAdd into pre-zeroed slots.
//        Split pairs have l1>=6 -> no POWER entries -> split is exact.
template<int PI, int CK>
__device__ __attribute__((always_inline)) inline void do_pair(
    const float* __restrict__ lds, float* __restrict__ stage, int lane2)
{
  constexpr P2 pe = pair_of(PI);
  constexpr int L1 = pe.l1, L2 = pe.l2;
  constexpr int LOmin = L2-L1;
  constexpr int LOmax = (L1+L2<LMAX)?(L1+L2):LMAX;
  constexpr int NLO = LOmax-LOmin+1;
  constexpr int B1 = tri_(L1), B2 = tri_(L2);
  constexpr int AH = L1/2;
  constexpr auto tab = make_cgtab<L1,L2>();

  // register-cache raw F1 (chunk-restricted |m| range) and F2 (full)
  f32x2 X1[L1+1], Y1[L1+1], X2[L2+1], Y2[L2+1];
#pragma unroll
  for (int a=0;a<=L1;a++){
    if (CK==1 && a>AH) continue;
    if (CK==2 && a<=AH) continue;
    X1[a] = *(const f32x2*)&lds[(B1+a)*ESTR + lane2];
    Y1[a] = *(const f32x2*)&lds[PLANE + (B1+a)*ESTR + lane2];
  }
#pragma unroll
  for (int a=0;a<=L2;a++){
    X2[a] = *(const f32x2*)&lds[(B2+a)*ESTR + lane2];
    Y2[a] = *(const f32x2*)&lds[PLANE + (B2+a)*ESTR + lane2];
  }

  f32x2 bAcc[NLO], pAcc[NLO];
#pragma unroll
  for (int t=0;t<NLO;t++){ bAcc[t]=f32x2{0.f,0.f}; pAcc[t]=f32x2{0.f,0.f}; }

#pragma unroll
  for (int M=-LOmax; M<=LOmax; M++){
    if (ck_dn(CK,L1,L2,M)==0) continue;     // folds after unroll
    const int m1lo = (M-L2 > -L1) ? (M-L2) : -L1;
    const int m1hi = (M+L2 <  L1) ? (M+L2) :  L1;
    f32x2 Prd[2*L1+1], Pid[2*L1+1];
#pragma unroll
    for (int m1=-L1; m1<=L1; m1++){
      if (m1<m1lo || m1>m1hi) continue;     // folds after unroll
      if (!in_ck(CK,L1,m1)) continue;       // folds after unroll
      const int m2 = M-m1;
      const int a1 = m1<0?-m1:m1, a2 = m2<0?-m2:m2;
      const int s1 = sr_(m1)*sr_(m2);
      const int s2 = -(sq_(m1)*sq_(m2));
      const int s3 = sr_(m1)*sq_(m2);
      const int s4 = sq_(m1)*sr_(m2);
      f32x2 t1 = (s1>0? X1[a1] : -X1[a1]) * X2[a2];
      Prd[m1+L1] = __builtin_elementwise_fma((s2>0? Y1[a1] : -Y1[a1]), Y2[a2], t1);
      f32x2 t2 = (s3>0? X1[a1] : -X1[a1]) * Y2[a2];
      Pid[m1+L1] = __builtin_elementwise_fma((s4>0? Y1[a1] : -Y1[a1]), X2[a2], t2);
    }
#pragma unroll
    for (int lo=LOmin; lo<=LOmax; lo++){
      if (lo < (M<0?-M:M)) continue;        // G_M only exists for |M|<=lo
      f32x2 Gr = {0.f,0.f}, Gi = {0.f,0.f};
      bool used = false;                    // constant-folds after unroll
#pragma unroll
      for (int m1=-L1; m1<=L1; m1++){
        if (m1<m1lo || m1>m1hi) continue;
        if (!in_ck(CK,L1,m1)) continue;
        const float C = tab.c[lo-LOmin][M+LOmax][m1+L1];
        if (C != 0.f){
          used = true;
          f32x2 Cv = {C,C};
          Gr = __builtin_elementwise_fma(Cv, Prd[m1+L1], Gr);
          Gi = __builtin_elementwise_fma(Cv, Pid[m1+L1], Gi);
        }
      }
      if (used){
        // beta += Re(G_M * conj(F3_M)); F3_M = (sr*x3, sq*y3), x3/y3 at |M|
        const int aM = M<0?-M:M;
        const int B3 = tri_(lo);
        f32x2 x3 = *(const f32x2*)&lds[(B3+aM)*ESTR + lane2];
        f32x2 y3 = *(const f32x2*)&lds[PLANE + (B3+aM)*ESTR + lane2];
        const int AL = sr_(M), BE = sq_(M); // fold after unroll
        bAcc[lo-LOmin] = __builtin_elementwise_fma(Gr, (AL>0? x3 : -x3), bAcc[lo-LOmin]);
        bAcc[lo-LOmin] = __builtin_elementwise_fma(Gi, (BE>0? y3 : -y3), bAcc[lo-LOmin]);
        if (power_idx(L1,L2,lo) >= 0){      // compile-time condition
          pAcc[lo-LOmin] = __builtin_elementwise_fma(Gr, Gr, pAcc[lo-LOmin]);
          pAcc[lo-LOmin] = __builtin_elementwise_fma(Gi, Gi, pAcc[lo-LOmin]);
        }
      }
    }
  }

  // emit to LDS stage ([slot][elem]); CK==0 pairs own their slots (plain
  // write); CK>0 chunks ds_add into slots pre-zeroed by flush A.
#pragma unroll
  for (int lo=LOmin; lo<=LOmax; lo++){
    const int fr   = full_rank(L1,L2,lo);
    const int slot = fr<FSPLIT ? fr : fr-FSPLIT;   // phase-1 pairs all have fr<100
    const int pidx = power_idx(L1,L2,lo);
    if (CK==0){
      *(f32x2*)&stage[slot*ESTR + lane2] = bAcc[lo-LOmin];
      if (pidx>=0)
        *(f32x2*)&stage[(PSLOT+pidx)*ESTR + lane2] = pAcc[lo-LOmin];
    } else {
      atomicAdd(&stage[slot*ESTR + lane2],     bAcc[lo-LOmin][0]);
      atomicAdd(&stage[slot*ESTR + lane2 + 1], bAcc[lo-LOmin][1]);
      // no POWER entries for split pairs (l1>=6) — compile-time guaranteed
    }
  }
}

// ---- masked unit dispatch (per-wave LPT bitmask schedule) ------------------
template<int U>
__device__ __attribute__((always_inline)) inline void unit_step(
    const float* __restrict__ lds, float* __restrict__ stage, int lane2,
    unsigned long long mk)
{
  if ((mk>>U)&1ull) do_pair<unit_pair(U), unit_chunk(U)>(lds, stage, lane2);  // wave-uniform
}
template<int OFF, int... Us>
__device__ __attribute__((always_inline)) inline void unit_range(
    std::integer_sequence<int,Us...>,
    const float* __restrict__ lds, float* __restrict__ stage, int lane2,
    unsigned long long mk)
{
  (unit_step<OFF+Us>(lds, stage, lane2, mk), ...);
}

struct Msk { unsigned long long m[8]; };   // bits 0..29 phase1, 30..50 phase2

constexpr int LDS_FLOATS = 2*PLANE + NSLOT*ESTR;
constexpr int LDS_BYTES  = LDS_FLOATS*4;   // 124,280 B
static_assert(LDS_BYTES <= 160*1024, "LDS over 160KB");

// __launch_bounds__ with NO min-waves arg: LDS already caps at 1 block/CU
// (8 waves), so the allocator may use up to 256 VGPR/wave at zero occupancy
// cost. The old ",2" capped VGPR at 128 and forced the spills seen in
// rounds 0/4 (FETCH/WRITE >> ideal).
__global__ __launch_bounds__(TPB) void main_kernel(
    const float* __restrict__ re, const float* __restrict__ im,
    float* __restrict__ out, Msk msk)
{
  extern __shared__ float lds[];
  float* stage = lds + 2*PLANE;
  const int gbase = blockIdx.x*EPB;

  // stage the m<=l triangle of 128 elements into [coeff][elem] planes
  for (int t=threadIdx.x; t<EPB*81; t+=TPB){
    float vr = re[(size_t)gbase*81 + t];
    float vi = im[(size_t)gbase*81 + t];
    int elem = t/81, x = t - elem*81;
    int l = x/9, m = x - l*9;
    if (m<=l){
      int off = tri_(l)+m;
      lds[off*ESTR+elem] = vr;
      lds[PLANE + off*ESTR+elem] = vi;
    }
  }
  __syncthreads();

  const int lane  = threadIdx.x & 63;
  const int wv    = __builtin_amdgcn_readfirstlane(threadIdx.x >> 6);
  const int lane2 = lane*2;
  const unsigned long long mk = msk.m[wv];
  const long long obase = (long long)gbase*NENT;

  // phase 1: units [0,30) = pairs with l1<=3, all CK==0 (plain writes)
  unit_range<0>(std::make_integer_sequence<int,P1END>{}, lds, stage, lane2, mk);
  __syncthreads();

  // flush A: out entries [0,100); zero slots [0,115) for phase-2 accumulation
  // (each (o,elem) touched by exactly one thread -> no race). POWER slots
  // [115,149) hold phase-1 results and are NOT zeroed.
  for (int p=threadIdx.x; p<EPB*PSLOT; p+=TPB){
    int elem = p/PSLOT, o = p - elem*PSLOT;
    float v = stage[o*ESTR + elem];
    stage[o*ESTR + elem] = 0.f;
    if (o < FSPLIT)
      out[obase + (long long)elem*NENT + o] = v;
  }
  __syncthreads();

  // phase 2: units [30,51) = pairs with l1>=4; l1>=6 pairs split into two
  // |m1|-chunks (atomicAdd into the zeroed slots)
  unit_range<P1END>(std::make_integer_sequence<int,NUNITS-P1END>{},
                    lds, stage, lane2, mk);
  __syncthreads();

  // flush B: out entries [100,249) <- slots [0,149) (coalesced 596B runs)
  for (int p=threadIdx.x; p<EPB*NSLOT; p+=TPB){
    int elem = p/NSLOT, o = p - elem*NSLOT;
    out[obase + (long long)elem*NENT + FSPLIT + o] = stage[o*ESTR + elem];
  }
}

// ================= host ====================================================
extern "C" void kernel_launch(void* const* d_in, const int* in_sizes, int n_in,
                              void* d_out, int out_size, void* d_ws, size_t ws_size,
                              hipStream_t stream) {
  const float* re = (const float*)d_in[0];
  const float* im = (const float*)d_in[1];
  float* out = (float*)d_out;
  const int batch = in_sizes[0] / 81;

  hipFuncSetAttribute((const void*)main_kernel,
                      hipFuncAttributeMaxDynamicSharedMemorySize, LDS_BYTES);

  // per-wave LPT schedule within each phase over the 51 units
  Msk msk{};
  {
    double uw[NUNITS]; int order[NUNITS];
    for (int u=0;u<NUNITS;u++){
      uw[u] = pair_w_ck(unit_pair(u), unit_chunk(u));
      order[u] = u;
    }
    for (int i=0;i<NUNITS;i++){           // selection sort desc by weight
      int mx=i;
      for (int j=i+1;j<NUNITS;j++) if (uw[order[j]]>uw[order[mx]]) mx=j;
      int t=order[i]; order[i]=order[mx]; order[mx]=t;
    }
    double loadA[8]={}, loadB[8]={};
    for (int i=0;i<NUNITS;i++){
      int u = order[i];
      if (u < P1END){
        int b=0; for (int j=1;j<8;j++) if (loadA[j]<loadA[b]) b=j;
        msk.m[b] |= 1ull<<u; loadA[b] += uw[u];
      } else {
        int b=0; for (int j=1;j<8;j++) if (loadB[j]<loadB[b]) b=j;
        msk.m[b] |= 1ull<<u; loadB[b] += uw[u];
      }
    }
  }

  main_kernel<<<batch/EPB, TPB, LDS_BYTES, stream>>>(re, im, out, msk);
}